// Round 4
// baseline (347.089 us; speedup 1.0000x reference)
//
#include <hip/hip_runtime.h>
#include <math.h>

#define BB 32
#define CC 256
#define HH 56
#define WW 56
#define KP 49      // 7*7 output pixels of the small convs
#define CMID 64    // C // RED
#define HW 3136    // 56*56

// -------- K0: transpose weights to channel-last for lane=cout coalescing -----
__global__ __launch_bounds__(256) void transpose_w_kernel(const float* __restrict__ w1,
                                                          const float* __restrict__ w2,
                                                          float* __restrict__ w1t,
                                                          float* __restrict__ w2t) {
    int tid = blockIdx.x * 256 + threadIdx.x;
    if (tid < 147456) {
        int co = tid & 63, ct = tid >> 6;
        w1t[tid] = w1[co * 2304 + ct];
    }
    if (tid < 294912) {
        int co = tid & 511, ct = tid >> 9;
        w2t[tid] = w2[co * 576 + ct];
    }
}

// ------------- K1: adaptive avg pool, no LDS: wave = plane, lane = window -----
__global__ __launch_bounds__(256) void pool_kernel(const float* __restrict__ x,
                                                   float* __restrict__ pooled) {
    int wv = threadIdx.x >> 6, lane = threadIdx.x & 63;
    int g = blockIdx.x * 4 + wv;            // plane id = b*256 + c
    if (lane < KP) {
        int ko = lane / 7, kw = lane - ko * 7;
        const float* base = x + (size_t)g * HW + (ko * 8) * WW + kw * 8;
        float s = 0.f;
        #pragma unroll
        for (int r = 0; r < 8; ++r) {
            float4 a = *(const float4*)(base + r * WW);
            float4 b4 = *(const float4*)(base + r * WW + 4);
            s += a.x + a.y + a.z + a.w + b4.x + b4.y + b4.z + b4.w;
        }
        pooled[(size_t)g * KP + lane] = s * (1.f / 64.f);
    }
}

// ---- K2a: conv3x3 (256->64) split-K x4 -> partials p1[z][b][co][49] ----
__global__ __launch_bounds__(512) void conv1_part_kernel(const float* __restrict__ pooled,
                                                         const float* __restrict__ w1t,
                                                         float* __restrict__ p1) {
    int y = blockIdx.x, b = blockIdx.y, z = blockIdx.z;   // z: cin slice of 64
    int wvu = __builtin_amdgcn_readfirstlane(threadIdx.x >> 6);  // 0..7
    int co = threadIdx.x & 63;
    __shared__ float red[8][7][64];
    float acc[7] = {0.f, 0.f, 0.f, 0.f, 0.f, 0.f, 0.f};
    const float* pb = pooled + (size_t)b * CC * KP;
    #pragma unroll 2
    for (int ci = 0; ci < 8; ++ci) {
        int cin = z * 64 + wvu * 8 + ci;
        const float* prow_base = pb + cin * KP;              // scalar base
        const float* wbase = w1t + (size_t)(cin * 9) * 64 + co;
        #pragma unroll
        for (int ky = 0; ky < 3; ++ky) {
            int iy = y + ky - 1;
            if (0 <= iy && iy < 7) {                         // uniform branch
                float s[9];
                s[0] = 0.f; s[8] = 0.f;
                const float* pr = prow_base + iy * 7;        // -> s_load
                #pragma unroll
                for (int j = 0; j < 7; ++j) s[j + 1] = pr[j];
                const float* wr = wbase + ky * 3 * 64;
                float w0 = wr[0], w1v = wr[64], w2v = wr[128];
                #pragma unroll
                for (int xx = 0; xx < 7; ++xx)
                    acc[xx] += s[xx] * w0 + s[xx + 1] * w1v + s[xx + 2] * w2v;
            }
        }
    }
    #pragma unroll
    for (int xx = 0; xx < 7; ++xx) red[wvu][xx][co] = acc[xx];
    __syncthreads();
    if (threadIdx.x < 448) {
        int xx = threadIdx.x >> 6, c2 = threadIdx.x & 63;
        float tot = 0.f;
        #pragma unroll
        for (int w = 0; w < 8; ++w) tot += red[w][xx][c2];
        p1[(size_t)z * 100352 + ((size_t)(b * CMID + c2)) * KP + y * 7 + xx] = tot;
    }
}

// ---- K2b: epilogue: sum 4 slices + BN + exact GELU -> hmid ----
__global__ __launch_bounds__(256) void conv1_epi_kernel(const float* __restrict__ p1,
                                                        const float* __restrict__ gamma,
                                                        const float* __restrict__ beta,
                                                        float* __restrict__ hmid) {
    int idx = blockIdx.x * 256 + threadIdx.x;
    if (idx < 100352) {
        float tot = p1[idx] + p1[idx + 100352] + p1[idx + 200704] + p1[idx + 301056];
        int co = (idx / KP) & 63;
        float bnscale = gamma[co] * rsqrtf(1.f + 1e-5f);
        float h = tot * bnscale + beta[co];
        float g = 0.5f * h * (1.f + erff(h * 0.70710678118654752440f));
        hmid[idx] = g;
    }
}

// ---- K3a: conv3x3 (64->512) split-K x2 -> partials pA/pB[z][b][c][49] ----
__global__ __launch_bounds__(512) void conv2_part_kernel(const float* __restrict__ hmid,
                                                         const float* __restrict__ w2t,
                                                         float* __restrict__ pA,
                                                         float* __restrict__ pB) {
    int y = blockIdx.x, b = blockIdx.y, z = blockIdx.z;   // z: cin slice of 32
    int gu = __builtin_amdgcn_readfirstlane(threadIdx.x >> 8);   // 0/1
    int co = threadIdx.x & 255;
    __shared__ float redA[2][7][256];
    __shared__ float redB[2][7][256];
    float a0[7] = {}, a1[7] = {};
    const float* hb = hmid + (size_t)b * CMID * KP;
    #pragma unroll 2
    for (int ci = 0; ci < 16; ++ci) {
        int cin = z * 32 + gu * 16 + ci;
        const float* hrow_base = hb + cin * KP;              // scalar base
        const float* wbase = w2t + (size_t)(cin * 9) * 512 + co;
        #pragma unroll
        for (int ky = 0; ky < 3; ++ky) {
            int iy = y + ky - 1;
            if (0 <= iy && iy < 7) {                         // uniform branch
                float s[9];
                s[0] = 0.f; s[8] = 0.f;
                const float* hr = hrow_base + iy * 7;        // -> s_load
                #pragma unroll
                for (int j = 0; j < 7; ++j) s[j + 1] = hr[j];
                const float* wr = wbase + ky * 3 * 512;
                float wa0 = wr[0],    wb0 = wr[256];
                float wa1 = wr[512],  wb1 = wr[768];
                float wa2 = wr[1024], wb2 = wr[1280];
                #pragma unroll
                for (int xx = 0; xx < 7; ++xx) {
                    float v0 = s[xx], v1 = s[xx + 1], v2 = s[xx + 2];
                    a0[xx] += v0 * wa0 + v1 * wa1 + v2 * wa2;
                    a1[xx] += v0 * wb0 + v1 * wb1 + v2 * wb2;
                }
            }
        }
    }
    #pragma unroll
    for (int xx = 0; xx < 7; ++xx) { redA[gu][xx][co] = a0[xx]; redB[gu][xx][co] = a1[xx]; }
    __syncthreads();
    if (threadIdx.x < 256) {
        int c = threadIdx.x;
        size_t base = (size_t)z * 401408 + ((size_t)(b * CC + c)) * KP + y * 7;
        #pragma unroll
        for (int xx = 0; xx < 7; ++xx) {
            pA[base + xx] = redA[0][xx][c] + redA[1][xx][c];
            pB[base + xx] = redB[0][xx][c] + redB[1][xx][c];
        }
    }
}

// ---- K3b: epilogue: sum 2 slices + bias + softmax(G=2) + wdyn mix -> dynw ----
__global__ __launch_bounds__(256) void conv2_epi_kernel(const float* __restrict__ pA,
                                                        const float* __restrict__ pB,
                                                        const float* __restrict__ b2,
                                                        const float* __restrict__ wdyn,
                                                        float* __restrict__ dynw) {
    int idx = blockIdx.x * 256 + threadIdx.x;
    if (idx < 401408) {
        int pix = idx % KP;
        int c = (idx / KP) & 255;
        float s0 = pA[idx] + pA[idx + 401408] + b2[c];
        float s1 = pB[idx] + pB[idx + 401408] + b2[c + CC];
        float m = fmaxf(s0, s1);
        float e0 = expf(s0 - m), e1 = expf(s1 - m);
        float wd0 = wdyn[c * KP + pix];
        float wd1 = wdyn[(CC + c) * KP + pix];
        dynw[idx] = (e0 * wd0 + e1 * wd1) / (e0 + e1);
    }
}

// --------- K4: depthwise 7x7, no LDS: wave = 8 rows x 56 cols, lane = col ----
// Input rows streamed; column shifts via ds_bpermute (__shfl). Lanes 56..63
// carry zeros, and negative shifts wrap to them -> free boundary handling.
__global__ __launch_bounds__(448) void dwconv_kernel(const float* __restrict__ x,
                                                     const float* __restrict__ dynw,
                                                     float* __restrict__ out) {
    int plane = blockIdx.x;                 // b*256 + c, 0..8191
    int wv = threadIdx.x >> 6;              // 0..6 : output row tile
    int lane = threadIdx.x & 63;
    const float* wp = dynw + (size_t)plane * KP;   // uniform -> s_loads
    float w[49];
    #pragma unroll
    for (int i = 0; i < 49; ++i) w[i] = wp[i];
    int r0 = wv << 3;
    const float* xp = x + (size_t)plane * HW;
    float* op = out + (size_t)plane * HW;
    float acc[8] = {};
    bool active = lane < WW;
    #pragma unroll
    for (int i = 0; i < 14; ++i) {
        int ir = r0 + i - 3;                // input row (wave-uniform)
        float v = 0.f;
        if (0 <= ir && ir < HH && active) v = xp[ir * WW + lane];
        float sh[7];
        sh[0] = __shfl(v, (lane - 3) & 63);
        sh[1] = __shfl(v, (lane - 2) & 63);
        sh[2] = __shfl(v, (lane - 1) & 63);
        sh[3] = v;
        sh[4] = __shfl(v, (lane + 1) & 63);
        sh[5] = __shfl(v, (lane + 2) & 63);
        sh[6] = __shfl(v, (lane + 3) & 63);
        #pragma unroll
        for (int ky = 0; ky < 7; ++ky) {
            int oy = i - ky;                // compile-time after unroll
            if (0 <= oy && oy < 8) {
                #pragma unroll
                for (int kx = 0; kx < 7; ++kx)
                    acc[oy] += sh[kx] * w[ky * 7 + kx];
            }
        }
    }
    if (active) {
        #pragma unroll
        for (int o = 0; o < 8; ++o)
            op[(r0 + o) * WW + lane] = acc[o];
    }
}

extern "C" void kernel_launch(void* const* d_in, const int* in_sizes, int n_in,
                              void* d_out, int out_size, void* d_ws, size_t ws_size,
                              hipStream_t stream) {
    const float* x     = (const float*)d_in[0];  // (32,256,56,56)
    const float* wdyn  = (const float*)d_in[1];  // (2,256,7,7)
    const float* w1    = (const float*)d_in[2];  // (64,256,3,3)
    const float* gamma = (const float*)d_in[3];  // (64,)
    const float* beta  = (const float*)d_in[4];  // (64,)
    const float* w2    = (const float*)d_in[5];  // (512,64,3,3)
    const float* b2    = (const float*)d_in[6];  // (512,)
    float* out = (float*)d_out;

    float* ws     = (float*)d_ws;
    float* hmid   = ws;               // 100352
    float* dynw   = ws + 100352;      // 401408
    float* w1t    = ws + 501760;      // 147456
    float* w2t    = ws + 649216;      // 294912
    float* pooled = ws + 944128;      // 401408   (dead after conv1_part)
    float* p1     = ws + 1345536;     // 401408   (dead after conv1_epi)
    float* pA     = ws + 944128;      // 802816   overlays pooled+p1
    float* pB     = ws + 1746944;     // 802816   (total 2549760 fl = 10.2 MB)

    transpose_w_kernel<<<dim3(1152),         256, 0, stream>>>(w1, w2, w1t, w2t);
    pool_kernel       <<<dim3(BB * CC / 4),  256, 0, stream>>>(x, pooled);
    conv1_part_kernel <<<dim3(7, BB, 4),     512, 0, stream>>>(pooled, w1t, p1);
    conv1_epi_kernel  <<<dim3(392),          256, 0, stream>>>(p1, gamma, beta, hmid);
    conv2_part_kernel <<<dim3(7, BB, 2),     512, 0, stream>>>(hmid, w2t, pA, pB);
    conv2_epi_kernel  <<<dim3(1568),         256, 0, stream>>>(pA, pB, b2, wdyn, dynw);
    dwconv_kernel     <<<dim3(BB * CC),      448, 0, stream>>>(x, dynw, out);
}